// Round 6
// baseline (248.115 us; speedup 1.0000x reference)
//
#include <hip/hip_runtime.h>

#define HH   224
#define WW   224
#define HW_  (HH * WW)
#define TS   16
#define TSH  18
#define NPIX (TSH * TSH)      // 324
#define XROW 144              // bytes per pixel row: 64ch*2B=128 data + 16 pad (16B-aligned)

typedef __attribute__((ext_vector_type(8))) short bf16x8;
typedef __attribute__((ext_vector_type(4))) short bf16x4;
typedef __attribute__((ext_vector_type(4))) float f32x4;

static __device__ __forceinline__ unsigned short f2bf(float f) {
    unsigned u = __float_as_uint(f);
    u += 0x7FFFu + ((u >> 16) & 1u);          // RNE
    return (unsigned short)(u >> 16);
}
static __device__ __forceinline__ float bf2f(unsigned short h) {
    return __uint_as_float(((unsigned)h) << 16);
}

// ---- pre-kernel: w1 -> bf16 [64][64]; w2 -> bf16 padded [64 ch][16 rows][64 o],
//      rows 9..15 zeroed so GEMM2 A-fragment loads are branchless ----
__global__ __launch_bounds__(256) void prep_weights(
    const float* __restrict__ w1, const float* __restrict__ w2,
    unsigned short* __restrict__ wsb)
{
    const int i = blockIdx.x * 256 + threadIdx.x;   // 0..65535
    unsigned short* w1b = wsb;                      // 4096 bf16
    unsigned short* w2p = wsb + 4096;               // 65536 bf16
    if (i < 4096) w1b[i] = f2bf(w1[i]);
    const int c  = i >> 10;
    const int rr = (i >> 6) & 15;
    const int o  = i & 63;
    float v = (rr < 9) ? w2[(c * 9 + rr) * 64 + o] : 0.f;
    w2p[i] = f2bf(v);
}

// LDS: xs only, [pix 0..323][64 ch bf16 + pad] = 324*144 = 46,656 B -> 3 blocks/CU
__global__ __launch_bounds__(256, 3) void dynconv_mfma16(
    const float* __restrict__ x, const unsigned short* __restrict__ wsb,
    float* __restrict__ out)
{
    __shared__ __align__(16) unsigned char xsb[NPIX * XROW];

    const unsigned char* w1b = (const unsigned char*)wsb;            // bf16 [64 o][64 c]
    const unsigned char* w2p = (const unsigned char*)(wsb + 4096);   // bf16 [64 ch][16 tap][64 o]

    const int b    = blockIdx.z;
    const int ty0  = blockIdx.y * TS;
    const int tx0  = blockIdx.x * TS;
    const int tid  = threadIdx.x;
    const int lane = tid & 63;
    const int w    = tid >> 6;      // wave 0..3 -> tile rows w*4..w*4+3
    const int tx   = lane & 15;
    const int g    = lane >> 4;

    const float* xb = x + (size_t)b * 64 * HW_;

    // ---- stage x tile (fp32 -> bf16), pixel-major [pix][c], channel pairs ----
    for (int i = tid; i < 32 * NPIX; i += 256) {
        int cp  = i / NPIX;          // channel pair 0..31
        int pix = i - cp * NPIX;
        int r   = pix / TSH;
        int col = pix - r * TSH;
        int gy  = ty0 + r - 1;
        int gx  = tx0 + col - 1;
        float f0 = 0.f, f1 = 0.f;
        if ((unsigned)gy < (unsigned)HH && (unsigned)gx < (unsigned)WW) {
            const float* p = xb + (size_t)(2 * cp) * HW_ + gy * WW + gx;
            f0 = p[0];
            f1 = p[HW_];
        }
        unsigned pk = (unsigned)f2bf(f0) | ((unsigned)f2bf(f1) << 16);
        *(unsigned*)(xsb + pix * XROW + cp * 4) = pk;
    }
    __syncthreads();

    // ---- GEMM1: h = relu(w1 . x) via 16x16x32; output packed straight into
    //      GEMM2 B-fragments bq[q][kb] (16x16x16 layout k=4g+j == C/D row=4g+r) ----
    bf16x4 bq[4][4];
    {
        bf16x8 aw1[4][2];
        #pragma unroll
        for (int mt = 0; mt < 4; ++mt)
            #pragma unroll
            for (int kt = 0; kt < 2; ++kt)
                aw1[mt][kt] = *(const bf16x8*)(w1b + (mt * 16 + tx) * 128 + kt * 64 + g * 16);
        #pragma unroll
        for (int q = 0; q < 4; ++q) {
            const int center = (w * 4 + q + 1) * TSH + (tx + 1);
            bf16x8 bx0 = *(const bf16x8*)(xsb + center * XROW + g * 16);        // c = g*8..g*8+7
            bf16x8 bx1 = *(const bf16x8*)(xsb + center * XROW + 64 + g * 16);   // c = 32+g*8..
            #pragma unroll
            for (int mt = 0; mt < 4; ++mt) {
                f32x4 hc = {0.f, 0.f, 0.f, 0.f};
                hc = __builtin_amdgcn_mfma_f32_16x16x32_bf16(aw1[mt][0], bx0, hc, 0, 0, 0);
                hc = __builtin_amdgcn_mfma_f32_16x16x32_bf16(aw1[mt][1], bx1, hc, 0, 0, 0);
                unsigned lo = (unsigned)f2bf(fmaxf(hc[0], 0.f)) | ((unsigned)f2bf(fmaxf(hc[1], 0.f)) << 16);
                unsigned hi = (unsigned)f2bf(fmaxf(hc[2], 0.f)) | ((unsigned)f2bf(fmaxf(hc[3], 0.f)) << 16);
                union { uint2 u; bf16x4 v; } cv;
                cv.u = make_uint2(lo, hi);
                bq[q][mt] = cv.v;    // h[o = mt*16 + 4g + j][pix(q,tx)]
            }
        }
    }

    // ---- patch pixel offsets per (q, r): tap k = g*4+r (taps >=9 have zero kern) ----
    int poff[4][4];
    #pragma unroll
    for (int q = 0; q < 4; ++q)
        #pragma unroll
        for (int r = 0; r < 4; ++r) {
            int kk = g * 4 + r;
            int kv = kk < 9 ? kk : 0;
            int dy = kv / 3;
            int dx = kv - dy * 3;
            poff[q][r] = (w * 4 + q + dy) * TSH + (tx + dx);
        }

    float* outp = out + (size_t)b * 64 * HW_ + (size_t)(ty0 + w * 4 + g) * WW + tx0 + tx;

    // ---- GEMM2 (16x16x16, A=w2 from global, B=bq regs) + tap contract, 2 ch/iter ----
    const unsigned char* w2l = w2p + tx * 128 + g * 8;   // + c*2048 + kb*32
    uint2 pf0[4], pf1[4];
    #pragma unroll
    for (int kb = 0; kb < 4; ++kb) {
        pf0[kb] = *(const uint2*)(w2l + kb * 32);
        pf1[kb] = *(const uint2*)(w2l + 2048 + kb * 32);
    }

    for (int c = 0; c < 64; c += 2) {
        union { uint2 u; bf16x4 v; } a2A[4], a2B[4];
        #pragma unroll
        for (int kb = 0; kb < 4; ++kb) { a2A[kb].u = pf0[kb]; a2B[kb].u = pf1[kb]; }
        const int cn = (c + 2 < 64) ? c + 2 : 62;
        #pragma unroll
        for (int kb = 0; kb < 4; ++kb) {
            pf0[kb] = *(const uint2*)(w2l + cn * 2048 + kb * 32);
            pf1[kb] = *(const uint2*)(w2l + (cn + 1) * 2048 + kb * 32);
        }

        f32x4 accA[4], accB[4];
        #pragma unroll
        for (int q = 0; q < 4; ++q) {
            accA[q] = f32x4{0.f, 0.f, 0.f, 0.f};
            accB[q] = f32x4{0.f, 0.f, 0.f, 0.f};
        }
        #pragma unroll
        for (int kb = 0; kb < 4; ++kb)
            #pragma unroll
            for (int q = 0; q < 4; ++q)
                accA[q] = __builtin_amdgcn_mfma_f32_16x16x16bf16_1k(a2A[kb].v, bq[q][kb], accA[q], 0, 0, 0);
        #pragma unroll
        for (int kb = 0; kb < 4; ++kb)
            #pragma unroll
            for (int q = 0; q < 4; ++q)
                accB[q] = __builtin_amdgcn_mfma_f32_16x16x16bf16_1k(a2B[kb].v, bq[q][kb], accB[q], 0, 0, 0);

        // one u32 LDS read serves both channels (c lo, c+1 hi)
        unsigned pp[4][4];
        #pragma unroll
        for (int q = 0; q < 4; ++q)
            #pragma unroll
            for (int r = 0; r < 4; ++r)
                pp[q][r] = *(const unsigned*)(xsb + poff[q][r] * XROW + c * 2);

        float pt[4], pu[4];
        #pragma unroll
        for (int q = 0; q < 4; ++q) {
            float s = 0.f, t = 0.f;
            #pragma unroll
            for (int r = 0; r < 4; ++r) {
                s = fmaf(accA[q][r], __uint_as_float(pp[q][r] << 16), s);
                t = fmaf(accB[q][r], __uint_as_float(pp[q][r] & 0xffff0000u), t);
            }
            s += __shfl_xor(s, 16, 64); s += __shfl_xor(s, 32, 64);
            t += __shfl_xor(t, 16, 64); t += __shfl_xor(t, 32, 64);
            pt[q] = s; pu[q] = t;
        }
        float vA = pt[0];
        vA = (g == 1) ? pt[1] : vA; vA = (g == 2) ? pt[2] : vA; vA = (g == 3) ? pt[3] : vA;
        float vB = pu[0];
        vB = (g == 1) ? pu[1] : vB; vB = (g == 2) ? pu[2] : vB; vB = (g == 3) ? pu[3] : vB;
        outp[(size_t)c * HW_] = vA;
        outp[(size_t)(c + 1) * HW_] = vB;
    }
}

extern "C" void kernel_launch(void* const* d_in, const int* in_sizes, int n_in,
                              void* d_out, int out_size, void* d_ws, size_t ws_size,
                              hipStream_t stream) {
    (void)in_sizes; (void)n_in; (void)out_size; (void)ws_size;
    const float* x  = (const float*)d_in[0];
    const float* w1 = (const float*)d_in[1];
    const float* w2 = (const float*)d_in[2];
    float* out = (float*)d_out;
    unsigned short* wsb = (unsigned short*)d_ws;    // 139,264 bytes used

    prep_weights<<<256, 256, 0, stream>>>(w1, w2, wsb);

    dim3 grid(WW / TS, HH / TS, 4);   // 14 x 14 x 4
    dynconv_mfma16<<<grid, 256, 0, stream>>>(x, wsb, out);
}